// Round 7
// baseline (317.072 us; speedup 1.0000x reference)
//
#include <hip/hip_runtime.h>
#include <math.h>

typedef __attribute__((ext_vector_type(8))) short short8;
typedef __attribute__((ext_vector_type(4))) float f32x4;
typedef __attribute__((ext_vector_type(4))) unsigned u32x4;

#define BB 8
#define CC 256
#define OO 256
#define HH 56
#define WW 56
#define HWH 3136
#define RED 16

__device__ inline unsigned short f2bf(float f) {
    unsigned u = __builtin_bit_cast(unsigned, f);
    u = (u + 0x7fffu + ((u >> 16) & 1u)) >> 16;
    return (unsigned short)u;
}
__device__ inline float bf2f(unsigned short h) {
    return __builtin_bit_cast(float, ((unsigned)h) << 16);
}
__device__ inline unsigned cvtpk(float lo, float hi) {
    unsigned r;
    asm("v_cvt_pk_bf16_f32 %0, %1, %2" : "=v"(r) : "v"(lo), "v"(hi));
    return r;
}
__device__ inline float fast_tanh(float x) {
    float e = __expf(2.0f * x);
    return 1.0f - 2.0f / (e + 1.0f);
}
__device__ inline void gl2lds16(const void* g, void* l) {
    __builtin_amdgcn_global_load_lds((const __attribute__((address_space(1))) unsigned int*)g,
                                     (__attribute__((address_space(3))) unsigned int*)l, 16, 0, 0);
}
// bilinear blend of 4 corner short8s -> bf16 short8 (32 fma + 4 cvt_pk)
__device__ inline short8 bilerp8(short8 q0, short8 q1, short8 q2, short8 q3, float4 w) {
    float f[8];
    #pragma unroll
    for (int e = 0; e < 8; ++e) {
        float fv = w.x * bf2f((unsigned short)q0[e]);
        fv = fmaf(w.y, bf2f((unsigned short)q1[e]), fv);
        fv = fmaf(w.z, bf2f((unsigned short)q2[e]), fv);
        fv = fmaf(w.w, bf2f((unsigned short)q3[e]), fv);
        f[e] = fv;
    }
    u32x4 pk;
    #pragma unroll
    for (int q = 0; q < 4; ++q) pk[q] = cvtpk(f[2 * q], f[2 * q + 1]);
    return __builtin_bit_cast(short8, pk);
}

// ---------------- SE: mean over H,W ----------------
__global__ __launch_bounds__(256) void se_mean(const float* __restrict__ x, float* __restrict__ y) {
    int bc = blockIdx.x;
    const float4* p = (const float4*)(x + (size_t)bc * HWH);
    float sum = 0.f;
    for (int i = threadIdx.x; i < HWH / 4; i += 256) {
        float4 v = p[i];
        sum += v.x + v.y + v.z + v.w;
    }
    __shared__ float sm[4];
    for (int off = 32; off > 0; off >>= 1) sum += __shfl_down(sum, off);
    if ((threadIdx.x & 63) == 0) sm[threadIdx.x >> 6] = sum;
    __syncthreads();
    if (threadIdx.x == 0) y[bc] = (sm[0] + sm[1] + sm[2] + sm[3]) * (1.0f / HWH);
}

// ---------------- SE: fc1->relu->fc2->sigmoid ----------------
__global__ __launch_bounds__(256) void se_fc(const float* __restrict__ y, const float* __restrict__ fc1,
                                             const float* __restrict__ fc2, float* __restrict__ s) {
    __shared__ float hbuf[BB * RED];
    int t = threadIdx.x;
    if (t < BB * RED) {
        int b = t / RED, r = t % RED;
        float acc = 0.f;
        for (int c = 0; c < CC; ++c) acc += y[b * CC + c] * fc1[r * CC + c];
        hbuf[t] = fmaxf(acc, 0.f);
    }
    __syncthreads();
    for (int i = t; i < BB * CC; i += 256) {
        int b = i / CC, c = i % CC;
        float acc = 0.f;
        #pragma unroll
        for (int r = 0; r < RED; ++r) acc += hbuf[b * RED + r] * fc2[c * RED + r];
        s[i] = 1.0f / (1.0f + expf(-acc));
    }
}

// ---------------- NCHW f32 -> NHWC bf16, scaled by s ----------------
__global__ __launch_bounds__(256) void prep_xt(const float* __restrict__ x, const float* __restrict__ s,
                                               unsigned short* __restrict__ x_t) {
    __shared__ float t[64][65];
    int blk = blockIdx.x;
    int ct = blk & 3;
    int hwt = (blk >> 2) % 49;
    int b = blk / (4 * 49);
    int c0 = ct * 64, hw0 = hwt * 64;
    int tid = threadIdx.x;
    const float* xb = x + ((size_t)(b * CC + c0)) * HWH + hw0;
    #pragma unroll
    for (int it = 0; it < 16; ++it) {
        int idx = it * 256 + tid;
        int c = idx >> 6, px = idx & 63;
        t[c][px] = xb[(size_t)c * HWH + px];
    }
    __syncthreads();
    unsigned short* xo = x_t + ((size_t)(b * HWH + hw0)) * CC + c0;
    #pragma unroll
    for (int it = 0; it < 16; ++it) {
        int idx = it * 256 + tid;
        int px = idx >> 6, c = idx & 63;
        xo[(size_t)px * CC + c] = f2bf(t[c][px] * s[b * CC + c0 + c]);
    }
}

// ---------------- deform weights -> per-MFMA-fragment contiguous 1KB chunks ----------------
// chunk = ((t*4 + og)*8 + f), f = n*2+kh ; byte addr = chunk*1024 + lane*16
// value = w_conv[o][c][kk]; o = og*64 + n*16 + (lane&15), c = (t&3)*64 + kh*32 + (lane>>4)*8 + e, kk = t>>2
__global__ __launch_bounds__(256) void prep_wcf(const float* __restrict__ w_conv, unsigned short* __restrict__ wbf) {
    int idx = blockIdx.x * 256 + threadIdx.x;   // 36*4*8*64 = 73728
    int lane = idx & 63;
    int f = (idx >> 6) & 7;
    int og = (idx >> 9) & 3;
    int t = idx >> 11;
    int kk = t >> 2, cc = t & 3;
    int n = f >> 1, kh = f & 1;
    int o = og * 64 + n * 16 + (lane & 15);
    int cb2 = cc * 64 + kh * 32 + ((lane >> 4) << 3);
    short8 r;
    #pragma unroll
    for (int e = 0; e < 8; ++e) r[e] = (short)f2bf(w_conv[(size_t)(o * 256 + cb2 + e) * 9 + kk]);
    *(short8*)(wbf + (size_t)idx * 8) = r;
}

// ---------------- offset weights -> 36 pre-swizzled 4KB tiles (o padded to 32) ----------------
__global__ __launch_bounds__(256) void prep_wo(const float* __restrict__ w_off, unsigned short* __restrict__ wbo) {
    int idx = blockIdx.x * 256 + threadIdx.x;    // 36*32*8 = 9216
    int g = idx & 7;
    int o = (idx >> 3) & 31;
    int t = idx >> 8;
    int kk = t >> 2, cc = t & 3;
    int dst = (((o * 128 + g * 16) ^ ((o & 7) << 4)) >> 1);
    short8 r;
    #pragma unroll
    for (int e = 0; e < 8; ++e) {
        int c = cc * 64 + g * 8 + e;
        r[e] = (o < 18) ? (short)f2bf(w_off[(size_t)(o * 256 + c) * 9 + kk]) : (short)0;
    }
    *(short8*)(wbo + (size_t)t * 2048 + dst) = r;
}

// ---------------- offset conv via MFMA: 784 blocks, 32px x 32o, 4 waves (2m x 2ksplit) ----------------
__global__ __launch_bounds__(256) void offset_mfma(const unsigned short* __restrict__ x_t,
                                                   const unsigned short* __restrict__ wbo,
                                                   const float* __restrict__ b_off,
                                                   float* __restrict__ offs) {
    __shared__ __align__(16) char As[4][4096];
    __shared__ __align__(16) char Bs[4][4096];
    __shared__ float red[128 * 8];
    int blk = blockIdx.x;
    blk = (blk & 7) * 98 + (blk >> 3);
    int b = blk / 98;
    int hw0 = (blk % 98) * 32;
    int tid = threadIdx.x;
    int lane = tid & 63, wv = tid >> 6;
    int ks = wv >> 1, m = wv & 1;
    int r0 = lane & 15, kb = (lane >> 4) << 4;
    int px = tid >> 3, c8 = tid & 7;
    int hwp = hw0 + px;
    int hp = hwp / 56, wp_ = hwp - hp * 56;
    int awoff = (px * 128 + c8 * 16) ^ ((px & 7) << 4);
    f32x4 zero = {0.f, 0.f, 0.f, 0.f};
    f32x4 acc[2] = {zero, zero};

    auto buildA = [&](int q, int r, int buf) {
        int t = q * 18 + r;
        int kk = t >> 2, cc = t & 3;
        int hh = hp + kk / 3 - 1, ww = wp_ + kk % 3 - 1;
        short8 v = {0, 0, 0, 0, 0, 0, 0, 0};
        if (hh >= 0 && hh < 56 && ww >= 0 && ww < 56)
            v = *(const short8*)(x_t + (((size_t)(b * HWH + hh * 56 + ww)) << 8) + cc * 64 + c8 * 8);
        *(short8*)(As[q * 2 + buf] + awoff) = v;
    };
    auto stageB = [&](int q, int r, int buf) {
        int t = q * 18 + r;
        gl2lds16(wbo + (size_t)t * 2048 + tid * 8, Bs[q * 2 + buf] + (tid >> 6) * 1024);
    };

    stageB(0, 0, 0); stageB(1, 0, 0);
    buildA(0, 0, 0); buildA(1, 0, 0);
    __syncthreads();

    #pragma unroll 2
    for (int r = 0; r < 18; ++r) {
        int cur = r & 1;
        if (r < 17) {
            stageB(0, r + 1, cur ^ 1); stageB(1, r + 1, cur ^ 1);
            buildA(0, r + 1, cur ^ 1); buildA(1, r + 1, cur ^ 1);
        }
        short8 a[2];
        #pragma unroll
        for (int kh = 0; kh < 2; ++kh) {
            int row = m * 16 + r0;
            int ao = (row * 128 + kh * 64 + kb) ^ ((row & 7) << 4);
            a[kh] = *(const short8*)(As[ks * 2 + cur] + ao);
        }
        #pragma unroll
        for (int n = 0; n < 2; ++n)
            #pragma unroll
            for (int kh = 0; kh < 2; ++kh) {
                int brow = n * 16 + r0;
                int bo = (brow * 128 + kh * 64 + kb) ^ ((brow & 7) << 4);
                short8 bv = *(const short8*)(Bs[ks * 2 + cur] + bo);
                acc[n] = __builtin_amdgcn_mfma_f32_16x16x32_bf16(a[kh], bv, acc[n], 0, 0, 0);
            }
        __syncthreads();
    }

    if (ks == 1) {
        #pragma unroll
        for (int n = 0; n < 2; ++n)
            *(f32x4*)&red[(m * 64 + lane) * 8 + n * 4] = acc[n];
    }
    __syncthreads();
    if (ks == 0) {
        #pragma unroll
        for (int n = 0; n < 2; ++n) {
            f32x4 o2 = *(const f32x4*)&red[(m * 64 + lane) * 8 + n * 4];
            acc[n] += o2;
            int o = n * 16 + r0;
            if (o < 18) {
                float bia = b_off[o];
                #pragma unroll
                for (int j = 0; j < 4; ++j)
                    offs[((size_t)(b * 18 + o)) * HWH + hw0 + m * 16 + ((lane >> 4) << 2) + j] = acc[n][j] + bia;
            }
        }
    }
}

// ---------------- precompute bilinear coords: bases (int4) + weights (float4) ----------------
__global__ __launch_bounds__(256) void coords_prep(const float* __restrict__ offs,
                                                   int4* __restrict__ ci, float4* __restrict__ cf) {
    int idx = blockIdx.x * 256 + threadIdx.x;    // 8*9*3136 = 225792
    int hw = idx % 3136;
    int t = idx / 3136;
    int kk = t % 9;
    int b = t / 9;
    int h = hw / 56, w = hw - h * 56;
    float dy = offs[((size_t)(b * 18 + kk * 2)) * HWH + hw];
    float dx = offs[((size_t)(b * 18 + kk * 2 + 1)) * HWH + hw];
    float ys = (float)(h - 1 + kk / 3) + dy;
    float xs = (float)(w - 1 + kk % 3) + dx;
    float y0f = floorf(ys), x0f = floorf(xs);
    float wy = ys - y0f, wx = xs - x0f;
    int y0 = (int)y0f, x0 = (int)x0f;
    int bi[4]; float wt[4];
    #pragma unroll
    for (int j = 0; j < 4; ++j) {
        int yj = y0 + (j >> 1), xj = x0 + (j & 1);
        bool val = yj >= 0 && yj < 56 && xj >= 0 && xj < 56;
        int yc = min(max(yj, 0), 55), xc = min(max(xj, 0), 55);
        wt[j] = val ? ((j >> 1) ? wy : 1.f - wy) * ((j & 1) ? wx : 1.f - wx) : 0.f;
        bi[j] = (b * HWH + yc * 56 + xc) << 8;
    }
    ci[idx] = make_int4(bi[0], bi[1], bi[2], bi[3]);
    cf[idx] = make_float4(wt[0], wt[1], wt[2], wt[3]);
}

// ---------------- deformable conv: barrier-free, LDS-free ----------------
// 784 blocks x 256 thr (4 waves). Block = 32px x 256o; wave og owns 32px x 64o.
// A-fragments built in-register via bilinear gather; B-fragments read from
// pre-packed global (per-fragment contiguous 1KB, L2-resident). No __syncthreads.
__global__ __launch_bounds__(256, 3) void deform_mfma(const unsigned short* __restrict__ x_t,
                                                      const int4* __restrict__ ci,
                                                      const float4* __restrict__ cf,
                                                      const unsigned short* __restrict__ wbf,
                                                      const float* __restrict__ b_conv,
                                                      float* __restrict__ out) {
    int blk = blockIdx.x;
    blk = (blk & 7) * 98 + (blk >> 3);           // 784 = 8*98, bijective XCD swizzle
    int b = blk / 98;
    int hw0 = (blk % 98) * 32;
    int tid = threadIdx.x;
    int lane = tid & 63, og = tid >> 6;
    int r0 = lane & 15, kg = lane >> 4;          // px-row within frag / k-slice
    int cidx0 = b * 9 * HWH + hw0 + r0;
    const char* wB = (const char*)wbf + og * 8192 + lane * 16;

    f32x4 zero = {0.f, 0.f, 0.f, 0.f};
    f32x4 acc[2][4];
    #pragma unroll
    for (int m = 0; m < 2; ++m)
        #pragma unroll
        for (int n = 0; n < 4; ++n) acc[m][n] = zero;

    int4 cb0 = ci[cidx0];
    int4 cb1 = ci[cidx0 + 16];
    float4 w0 = cf[cidx0];
    float4 w1 = cf[cidx0 + 16];

    #pragma unroll 1
    for (int kk = 0; kk < 9; ++kk) {
        // prefetch next-kk coords
        int4 nb0, nb1; float4 nw0, nw1;
        if (kk < 8) {
            int cidx = cidx0 + (kk + 1) * HWH;
            nb0 = ci[cidx]; nb1 = ci[cidx + 16];
            nw0 = cf[cidx]; nw1 = cf[cidx + 16];
        }
        // per-kk corner base pointers (lane-specific channel slice kg*8)
        const unsigned short* p00 = x_t + cb0.x + kg * 8;
        const unsigned short* p01 = x_t + cb0.y + kg * 8;
        const unsigned short* p02 = x_t + cb0.z + kg * 8;
        const unsigned short* p03 = x_t + cb0.w + kg * 8;
        const unsigned short* p10 = x_t + cb1.x + kg * 8;
        const unsigned short* p11 = x_t + cb1.y + kg * 8;
        const unsigned short* p12 = x_t + cb1.z + kg * 8;
        const unsigned short* p13 = x_t + cb1.w + kg * 8;
        const char* wk = wB + (size_t)kk * 131072;

        #pragma unroll
        for (int cc = 0; cc < 4; ++cc) {
            const char* wt_ = wk + cc * 32768;
            #pragma unroll
            for (int kh = 0; kh < 2; ++kh) {
                const int co = cc * 64 + kh * 32;    // shorts
                short8 q00 = *(const short8*)(p00 + co);
                short8 q01 = *(const short8*)(p01 + co);
                short8 q02 = *(const short8*)(p02 + co);
                short8 q03 = *(const short8*)(p03 + co);
                short8 q10 = *(const short8*)(p10 + co);
                short8 q11 = *(const short8*)(p11 + co);
                short8 q12 = *(const short8*)(p12 + co);
                short8 q13 = *(const short8*)(p13 + co);
                short8 bf0 = *(const short8*)(wt_ + (0 * 2 + kh) * 1024);
                short8 bf1 = *(const short8*)(wt_ + (1 * 2 + kh) * 1024);
                short8 bf2 = *(const short8*)(wt_ + (2 * 2 + kh) * 1024);
                short8 bf3 = *(const short8*)(wt_ + (3 * 2 + kh) * 1024);
                short8 a0 = bilerp8(q00, q01, q02, q03, w0);
                short8 a1 = bilerp8(q10, q11, q12, q13, w1);
                acc[0][0] = __builtin_amdgcn_mfma_f32_16x16x32_bf16(a0, bf0, acc[0][0], 0, 0, 0);
                acc[1][0] = __builtin_amdgcn_mfma_f32_16x16x32_bf16(a1, bf0, acc[1][0], 0, 0, 0);
                acc[0][1] = __builtin_amdgcn_mfma_f32_16x16x32_bf16(a0, bf1, acc[0][1], 0, 0, 0);
                acc[1][1] = __builtin_amdgcn_mfma_f32_16x16x32_bf16(a1, bf1, acc[1][1], 0, 0, 0);
                acc[0][2] = __builtin_amdgcn_mfma_f32_16x16x32_bf16(a0, bf2, acc[0][2], 0, 0, 0);
                acc[1][2] = __builtin_amdgcn_mfma_f32_16x16x32_bf16(a1, bf2, acc[1][2], 0, 0, 0);
                acc[0][3] = __builtin_amdgcn_mfma_f32_16x16x32_bf16(a0, bf3, acc[0][3], 0, 0, 0);
                acc[1][3] = __builtin_amdgcn_mfma_f32_16x16x32_bf16(a1, bf3, acc[1][3], 0, 0, 0);
            }
        }
        cb0 = nb0; cb1 = nb1; w0 = nw0; w1 = nw1;
    }

    // ---- epilogue: bias + tanh, NCHW float4 stores ----
    #pragma unroll
    for (int n = 0; n < 4; ++n) {
        int o = og * 64 + n * 16 + r0;
        float bia = b_conv[o];
        #pragma unroll
        for (int m = 0; m < 2; ++m) {
            int pxo = hw0 + m * 16 + (kg << 2);
            float4 v;
            v.x = fast_tanh(acc[m][n][0] + bia);
            v.y = fast_tanh(acc[m][n][1] + bia);
            v.z = fast_tanh(acc[m][n][2] + bia);
            v.w = fast_tanh(acc[m][n][3] + bia);
            *(float4*)(out + ((size_t)(b * OO + o)) * HWH + pxo) = v;
        }
    }
}

extern "C" void kernel_launch(void* const* d_in, const int* in_sizes, int n_in,
                              void* d_out, int out_size, void* d_ws, size_t ws_size,
                              hipStream_t stream) {
    const float* x      = (const float*)d_in[0];
    const float* w_off  = (const float*)d_in[1];
    const float* b_off  = (const float*)d_in[2];
    const float* w_conv = (const float*)d_in[3];
    const float* b_conv = (const float*)d_in[4];
    const float* fc1    = (const float*)d_in[5];
    const float* fc2    = (const float*)d_in[6];
    float* out = (float*)d_out;
    float* ws  = (float*)d_ws;

    float* y    = ws;                                  // 2048
    float* s    = y + 2048;                            // 2048
    float* offs = s + 2048;                            // 451584
    unsigned short* x_t = (unsigned short*)(offs + 451584);    // 6,422,528 shorts
    unsigned short* wbo = x_t + 6422528;                       // 73,728 shorts (swizzled tiles)
    unsigned short* wbf = wbo + 73728;                         // 589,824 shorts (frag chunks)
    int4*   ci = (int4*)(wbf + 589824);                        // 225,792 int4
    float4* cf = (float4*)(ci + 225792);                       // 225,792 float4

    se_mean<<<BB * CC, 256, 0, stream>>>(x, y);
    se_fc<<<1, 256, 0, stream>>>(y, fc1, fc2, s);
    prep_wcf<<<288, 256, 0, stream>>>(w_conv, wbf);
    prep_wo<<<36, 256, 0, stream>>>(w_off, wbo);
    prep_xt<<<BB * 49 * 4, 256, 0, stream>>>(x, s, x_t);
    offset_mfma<<<BB * 98, 256, 0, stream>>>(x_t, wbo, b_off, offs);
    coords_prep<<<882, 256, 0, stream>>>(offs, ci, cf);
    deform_mfma<<<BB * 98, 256, 0, stream>>>(x_t, ci, cf, wbf, b_conv, out);
}

// Round 8
// 137.333 us; speedup vs baseline: 2.3088x; 2.3088x over previous
//
#include <hip/hip_runtime.h>
#include <math.h>

typedef __attribute__((ext_vector_type(8))) short short8;
typedef __attribute__((ext_vector_type(4))) short s16x4;
typedef __attribute__((ext_vector_type(4))) float f32x4;

#define BB 8
#define CC 256
#define OO 256
#define HH 56
#define WW 56
#define HWH 3136
#define RED 16

__device__ inline unsigned short f2bf(float f) {
    unsigned u = __builtin_bit_cast(unsigned, f);
    u = (u + 0x7fffu + ((u >> 16) & 1u)) >> 16;
    return (unsigned short)u;
}
__device__ inline float bf2f(unsigned short h) {
    return __builtin_bit_cast(float, ((unsigned)h) << 16);
}
__device__ inline unsigned cvtpk(float lo, float hi) {
    unsigned r;
    asm("v_cvt_pk_bf16_f32 %0, %1, %2" : "=v"(r) : "v"(lo), "v"(hi));
    return r;
}
__device__ inline float fast_tanh(float x) {
    float e = __expf(2.0f * x);
    return 1.0f - 2.0f / (e + 1.0f);
}
__device__ inline void gl2lds16(const void* g, void* l) {
    __builtin_amdgcn_global_load_lds((const __attribute__((address_space(1))) unsigned int*)g,
                                     (__attribute__((address_space(3))) unsigned int*)l, 16, 0, 0);
}

// ---------------- zero y ----------------
__global__ __launch_bounds__(256) void zero_y(float* __restrict__ y) {
    y[blockIdx.x * 256 + threadIdx.x] = 0.f;
}

// ---------------- NCHW f32 -> NHWC bf16 (unscaled) + fused channel sums ----------------
__global__ __launch_bounds__(256) void prep_xt(const float* __restrict__ x, unsigned short* __restrict__ x_t,
                                               float* __restrict__ y) {
    __shared__ float t[64][65];
    int blk = blockIdx.x;
    int ct = blk & 3;
    int hwt = (blk >> 2) % 49;
    int b = blk / (4 * 49);
    int c0 = ct * 64, hw0 = hwt * 64;
    int tid = threadIdx.x;
    const float* xb = x + ((size_t)(b * CC + c0)) * HWH + hw0;
    #pragma unroll
    for (int it = 0; it < 16; ++it) {
        int idx = it * 256 + tid;
        int c = idx >> 6, px = idx & 63;
        t[c][px] = xb[(size_t)c * HWH + px];
    }
    __syncthreads();
    unsigned short* xo = x_t + ((size_t)(b * HWH + hw0)) * CC + c0;
    #pragma unroll
    for (int it = 0; it < 16; ++it) {
        int idx = it * 256 + tid;
        int px = idx >> 6, c = idx & 63;
        xo[(size_t)px * CC + c] = f2bf(t[c][px]);
    }
    // fused per-channel partial sums
    int c = tid >> 2, seg = tid & 3;
    float sum = 0.f;
    #pragma unroll
    for (int i = 0; i < 16; ++i) sum += t[c][seg * 16 + i];
    sum += __shfl_down(sum, 1);
    sum += __shfl_down(sum, 2);
    if (seg == 0) atomicAdd(&y[b * 256 + c0 + c], sum);
}

// ---------------- SE: fc1->relu->fc2->sigmoid (y holds sums) ----------------
__global__ __launch_bounds__(256) void se_fc(const float* __restrict__ y, const float* __restrict__ fc1,
                                             const float* __restrict__ fc2, float* __restrict__ s) {
    __shared__ float hbuf[BB * RED];
    const float inv = 1.0f / HWH;
    int t = threadIdx.x;
    if (t < BB * RED) {
        int b = t / RED, r = t % RED;
        float acc = 0.f;
        for (int c = 0; c < CC; ++c) acc += (y[b * CC + c] * inv) * fc1[r * CC + c];
        hbuf[t] = fmaxf(acc, 0.f);
    }
    __syncthreads();
    for (int i = t; i < BB * CC; i += 256) {
        int b = i / CC, c = i % CC;
        float acc = 0.f;
        #pragma unroll
        for (int r = 0; r < RED; ++r) acc += hbuf[b * RED + r] * fc2[c * RED + r];
        s[i] = 1.0f / (1.0f + expf(-acc));
    }
}

// ---------------- deform weights -> per-MFMA-fragment contiguous 1KB chunks (unscaled) ----------------
// addr(shorts) = ((t*8 + og)*4 + f)*512 + lane*8 ; f = n*2+kh
// value = w_conv[o][c][kk]; o = og*32 + n*16 + (lane&15), c = (t&3)*64 + kh*32 + (lane>>4)*8 + e, kk = t>>2
__global__ __launch_bounds__(256) void prep_wcf(const float* __restrict__ w_conv, unsigned short* __restrict__ wbf) {
    int idx = blockIdx.x * 256 + threadIdx.x;   // 73728
    int lane = idx & 63;
    int f = (idx >> 6) & 3;
    int og = (idx >> 8) & 7;
    int t = idx >> 11;
    int kk = t >> 2, cc = t & 3;
    int n = f >> 1, kh = f & 1;
    int o = og * 32 + n * 16 + (lane & 15);
    int cb2 = cc * 64 + kh * 32 + ((lane >> 4) << 3);
    short8 r;
    #pragma unroll
    for (int e = 0; e < 8; ++e) r[e] = (short)f2bf(w_conv[(size_t)(o * 256 + cb2 + e) * 9 + kk]);
    *(short8*)(wbf + (size_t)idx * 8) = r;
}

// ---------------- offset weights -> 36 pre-swizzled 4KB tiles (o padded to 32, unscaled) ----------------
__global__ __launch_bounds__(256) void prep_wo(const float* __restrict__ w_off, unsigned short* __restrict__ wbo) {
    int idx = blockIdx.x * 256 + threadIdx.x;    // 9216
    int g = idx & 7;
    int o = (idx >> 3) & 31;
    int t = idx >> 8;
    int kk = t >> 2, cc = t & 3;
    int dst = (((o * 128 + g * 16) ^ ((o & 7) << 4)) >> 1);
    short8 r;
    #pragma unroll
    for (int e = 0; e < 8; ++e) {
        int c = cc * 64 + g * 8 + e;
        r[e] = (o < 18) ? (short)f2bf(w_off[(size_t)(o * 256 + c) * 9 + kk]) : (short)0;
    }
    *(short8*)(wbo + (size_t)t * 2048 + dst) = r;
}

// ---------------- offset conv via MFMA: 784 blocks, 32px x 32o, A scaled by s from LDS ----------------
__global__ __launch_bounds__(256) void offset_mfma(const unsigned short* __restrict__ x_t,
                                                   const float* __restrict__ s,
                                                   const unsigned short* __restrict__ wbo,
                                                   const float* __restrict__ b_off,
                                                   float* __restrict__ offs) {
    __shared__ __align__(16) char As[4][4096];
    __shared__ __align__(16) char Bs[4][4096];
    __shared__ float red[128 * 8];
    __shared__ float s_lds[256];
    int blk = blockIdx.x;
    blk = (blk & 7) * 98 + (blk >> 3);
    int b = blk / 98;
    int hw0 = (blk % 98) * 32;
    int tid = threadIdx.x;
    int lane = tid & 63, wv = tid >> 6;
    int ks = wv >> 1, m = wv & 1;
    int r0 = lane & 15, kb = (lane >> 4) << 4;
    int px = tid >> 3, c8 = tid & 7;
    int hwp = hw0 + px;
    int hp = hwp / 56, wp_ = hwp - hp * 56;
    int awoff = (px * 128 + c8 * 16) ^ ((px & 7) << 4);
    f32x4 zero = {0.f, 0.f, 0.f, 0.f};
    f32x4 acc[2] = {zero, zero};

    s_lds[tid] = s[b * 256 + tid];
    __syncthreads();

    auto buildA = [&](int q, int r, int buf) {
        int t = q * 18 + r;
        int kk = t >> 2, cc = t & 3;
        int hh = hp + kk / 3 - 1, ww = wp_ + kk % 3 - 1;
        short8 v = {0, 0, 0, 0, 0, 0, 0, 0};
        if (hh >= 0 && hh < 56 && ww >= 0 && ww < 56)
            v = *(const short8*)(x_t + (((size_t)(b * HWH + hh * 56 + ww)) << 8) + cc * 64 + c8 * 8);
        float4 s0 = *(const float4*)&s_lds[cc * 64 + c8 * 8];
        float4 s1 = *(const float4*)&s_lds[cc * 64 + c8 * 8 + 4];
        float f0 = bf2f((unsigned short)v[0]) * s0.x;
        float f1 = bf2f((unsigned short)v[1]) * s0.y;
        float f2 = bf2f((unsigned short)v[2]) * s0.z;
        float f3 = bf2f((unsigned short)v[3]) * s0.w;
        float f4 = bf2f((unsigned short)v[4]) * s1.x;
        float f5 = bf2f((unsigned short)v[5]) * s1.y;
        float f6 = bf2f((unsigned short)v[6]) * s1.z;
        float f7 = bf2f((unsigned short)v[7]) * s1.w;
        *(uint4*)(As[q * 2 + buf] + awoff) =
            make_uint4(cvtpk(f0, f1), cvtpk(f2, f3), cvtpk(f4, f5), cvtpk(f6, f7));
    };
    auto stageB = [&](int q, int r, int buf) {
        int t = q * 18 + r;
        gl2lds16(wbo + (size_t)t * 2048 + tid * 8, Bs[q * 2 + buf] + (tid >> 6) * 1024);
    };

    stageB(0, 0, 0); stageB(1, 0, 0);
    buildA(0, 0, 0); buildA(1, 0, 0);
    __syncthreads();

    #pragma unroll 2
    for (int r = 0; r < 18; ++r) {
        int cur = r & 1;
        if (r < 17) {
            stageB(0, r + 1, cur ^ 1); stageB(1, r + 1, cur ^ 1);
            buildA(0, r + 1, cur ^ 1); buildA(1, r + 1, cur ^ 1);
        }
        short8 a[2];
        #pragma unroll
        for (int kh = 0; kh < 2; ++kh) {
            int row = m * 16 + r0;
            int ao = (row * 128 + kh * 64 + kb) ^ ((row & 7) << 4);
            a[kh] = *(const short8*)(As[ks * 2 + cur] + ao);
        }
        #pragma unroll
        for (int n = 0; n < 2; ++n)
            #pragma unroll
            for (int kh = 0; kh < 2; ++kh) {
                int brow = n * 16 + r0;
                int bo = (brow * 128 + kh * 64 + kb) ^ ((brow & 7) << 4);
                short8 bv = *(const short8*)(Bs[ks * 2 + cur] + bo);
                acc[n] = __builtin_amdgcn_mfma_f32_16x16x32_bf16(a[kh], bv, acc[n], 0, 0, 0);
            }
        __syncthreads();
    }

    if (ks == 1) {
        #pragma unroll
        for (int n = 0; n < 2; ++n)
            *(f32x4*)&red[(m * 64 + lane) * 8 + n * 4] = acc[n];
    }
    __syncthreads();
    if (ks == 0) {
        #pragma unroll
        for (int n = 0; n < 2; ++n) {
            f32x4 o2 = *(const f32x4*)&red[(m * 64 + lane) * 8 + n * 4];
            acc[n] += o2;
            int o = n * 16 + r0;
            if (o < 18) {
                float bia = b_off[o];
                #pragma unroll
                for (int j = 0; j < 4; ++j)
                    offs[((size_t)(b * 18 + o)) * HWH + hw0 + m * 16 + ((lane >> 4) << 2) + j] = acc[n][j] + bia;
            }
        }
    }
}

// ---------------- precompute bilinear coords: bases (int4) + weights (float4) ----------------
__global__ __launch_bounds__(256) void coords_prep(const float* __restrict__ offs,
                                                   int4* __restrict__ ci, float4* __restrict__ cf) {
    int idx = blockIdx.x * 256 + threadIdx.x;    // 225792
    int hw = idx % 3136;
    int t = idx / 3136;
    int kk = t % 9;
    int b = t / 9;
    int h = hw / 56, w = hw - h * 56;
    float dy = offs[((size_t)(b * 18 + kk * 2)) * HWH + hw];
    float dx = offs[((size_t)(b * 18 + kk * 2 + 1)) * HWH + hw];
    float ys = (float)(h - 1 + kk / 3) + dy;
    float xs = (float)(w - 1 + kk % 3) + dx;
    float y0f = floorf(ys), x0f = floorf(xs);
    float wy = ys - y0f, wx = xs - x0f;
    int y0 = (int)y0f, x0 = (int)x0f;
    int bi[4]; float wt[4];
    #pragma unroll
    for (int j = 0; j < 4; ++j) {
        int yj = y0 + (j >> 1), xj = x0 + (j & 1);
        bool val = yj >= 0 && yj < 56 && xj >= 0 && xj < 56;
        int yc = min(max(yj, 0), 55), xc = min(max(xj, 0), 55);
        wt[j] = val ? ((j >> 1) ? wy : 1.f - wy) * ((j & 1) ? wx : 1.f - wx) : 0.f;
        bi[j] = (b * HWH + yc * 56 + xc) << 8;
    }
    ci[idx] = make_int4(bi[0], bi[1], bi[2], bi[3]);
    cf[idx] = make_float4(wt[0], wt[1], wt[2], wt[3]);
}

// 4-channel bilinear blend (+ per-channel s) -> 8B bf16 LDS write
__device__ inline void blend_write(const s16x4* q, float4 w, const float* s4, char* dst) {
    float f0 = w.x * bf2f((unsigned short)q[0][0]);
    f0 = fmaf(w.y, bf2f((unsigned short)q[1][0]), f0);
    f0 = fmaf(w.z, bf2f((unsigned short)q[2][0]), f0);
    f0 = fmaf(w.w, bf2f((unsigned short)q[3][0]), f0);
    float f1 = w.x * bf2f((unsigned short)q[0][1]);
    f1 = fmaf(w.y, bf2f((unsigned short)q[1][1]), f1);
    f1 = fmaf(w.z, bf2f((unsigned short)q[2][1]), f1);
    f1 = fmaf(w.w, bf2f((unsigned short)q[3][1]), f1);
    float f2 = w.x * bf2f((unsigned short)q[0][2]);
    f2 = fmaf(w.y, bf2f((unsigned short)q[1][2]), f2);
    f2 = fmaf(w.z, bf2f((unsigned short)q[2][2]), f2);
    f2 = fmaf(w.w, bf2f((unsigned short)q[3][2]), f2);
    float f3 = w.x * bf2f((unsigned short)q[0][3]);
    f3 = fmaf(w.y, bf2f((unsigned short)q[1][3]), f3);
    f3 = fmaf(w.z, bf2f((unsigned short)q[2][3]), f3);
    f3 = fmaf(w.w, bf2f((unsigned short)q[3][3]), f3);
    *(uint2*)dst = make_uint2(cvtpk(f0 * s4[0], f1 * s4[1]), cvtpk(f2 * s4[2], f3 * s4[3]));
}

// ---------------- deformable conv: 784 blocks x 512 thr (8 waves), 32px x 256o ----------------
// wave og owns 32px x 32o (acc[2][2]); A staged in 8KB LDS dbuf (8B/thread bilinear items);
// B read as per-fragment contiguous global chunks. One barrier/step, r4-style prefetch distances.
__global__ __launch_bounds__(512) void deform_mfma(const unsigned short* __restrict__ x_t,
                                                   const float* __restrict__ s,
                                                   const int4* __restrict__ ci,
                                                   const float4* __restrict__ cf,
                                                   const unsigned short* __restrict__ wbf,
                                                   const float* __restrict__ b_conv,
                                                   float* __restrict__ out) {
    __shared__ __align__(16) char As[8192];      // 2 x 4KB (32px x 128B)
    __shared__ float s_lds[256];
    int blk = blockIdx.x;
    blk = (blk & 7) * 98 + (blk >> 3);           // bijective XCD swizzle (784 = 8*98)
    int b = blk / 98;
    int hw0 = (blk % 98) * 32;
    int tid = threadIdx.x;
    int lane = tid & 63, og = tid >> 6;
    int px = tid >> 4, cq = tid & 15;            // A-build: 32px x 16 groups of 4ch (8B)
    int r0 = lane & 15, kb = (lane >> 4) << 4;
    int awoff = (px * 128 + cq * 8) ^ ((px & 7) << 4);
    int cidx0 = b * 9 * HWH + hw0 + px;
    const unsigned short* wbB = wbf + og * 2048 + lane * 8;

    if (tid < 256) s_lds[tid] = s[b * 256 + tid];

    f32x4 zero = {0.f, 0.f, 0.f, 0.f};
    f32x4 acc[2][2];
    #pragma unroll
    for (int m = 0; m < 2; ++m)
        #pragma unroll
        for (int n = 0; n < 2; ++n) acc[m][n] = zero;

    int4 cbL = ci[cidx0];                        // kk0 (corner loads)
    float4 cwB = cf[cidx0];                      // kk0 (blend weights)
    int4 cbN = ci[cidx0 + HWH];                  // kk1 prefetch
    float4 cwN = cf[cidx0 + HWH];

    s16x4 crn0[4], crn1[4];
    short8 bv[4];

    __syncthreads();                             // s_lds ready

    // ---- prologue: blend step0 -> As[0]; load corners(step1); load B(0) ----
    {
        int c00 = cq * 4;                        // cc=0
        s16x4 q[4];
        q[0] = *(const s16x4*)(x_t + cbL.x + c00);
        q[1] = *(const s16x4*)(x_t + cbL.y + c00);
        q[2] = *(const s16x4*)(x_t + cbL.z + c00);
        q[3] = *(const s16x4*)(x_t + cbL.w + c00);
        int c01 = 64 + cq * 4;                   // cc=1 (step1)
        crn1[0] = *(const s16x4*)(x_t + cbL.x + c01);
        crn1[1] = *(const s16x4*)(x_t + cbL.y + c01);
        crn1[2] = *(const s16x4*)(x_t + cbL.z + c01);
        crn1[3] = *(const s16x4*)(x_t + cbL.w + c01);
        #pragma unroll
        for (int f = 0; f < 4; ++f) bv[f] = *(const short8*)(wbB + f * 512);
        blend_write(q, cwB, &s_lds[cq * 4], As + awoff);
    }
    __syncthreads();

#define DSTEP(T, CBLEND, CLOAD) { \
    short8 a_[2][2]; \
    { int tb_ = ((T) & 1) * 4096; \
      _Pragma("unroll") for (int m_ = 0; m_ < 2; ++m_) \
      _Pragma("unroll") for (int kh_ = 0; kh_ < 2; ++kh_) { \
        int row_ = m_ * 16 + r0; \
        int ao_ = (row_ * 128 + kh_ * 64 + kb) ^ ((row_ & 7) << 4); \
        a_[m_][kh_] = *(const short8*)(As + tb_ + ao_); } } \
    _Pragma("unroll") for (int n_ = 0; n_ < 2; ++n_) \
      _Pragma("unroll") for (int kh_ = 0; kh_ < 2; ++kh_) \
        _Pragma("unroll") for (int m_ = 0; m_ < 2; ++m_) \
          acc[m_][n_] = __builtin_amdgcn_mfma_f32_16x16x32_bf16(a_[m_][kh_], bv[n_ * 2 + kh_], acc[m_][n_], 0, 0, 0); \
    if ((T) < 35) { \
        const unsigned short* wp_ = wbB + (size_t)((T) + 1) * 16384; \
        _Pragma("unroll") for (int f_ = 0; f_ < 4; ++f_) bv[f_] = *(const short8*)(wp_ + f_ * 512); } \
    if ((T) < 35) { \
        if ((((T) + 1) & 3) == 0) cwB = cwN; \
        int ccB_ = ((T) + 1) & 3; \
        blend_write(CBLEND, cwB, &s_lds[ccB_ * 64 + cq * 4], As + (((T) + 1) & 1) * 4096 + awoff); } \
    if ((T) < 34) { \
        if ((((T) + 2) & 3) == 0) cbL = cbN; \
        int c0_ = (((T) + 2) & 3) * 64 + cq * 4; \
        CLOAD[0] = *(const s16x4*)(x_t + cbL.x + c0_); \
        CLOAD[1] = *(const s16x4*)(x_t + cbL.y + c0_); \
        CLOAD[2] = *(const s16x4*)(x_t + cbL.z + c0_); \
        CLOAD[3] = *(const s16x4*)(x_t + cbL.w + c0_); } \
    if ((((T) + 3) & 3) == 0 && ((T) + 3) < 36) { \
        int kkp_ = ((T) + 3) >> 2; \
        cbN = ci[cidx0 + kkp_ * HWH]; \
        cwN = cf[cidx0 + kkp_ * HWH]; } \
    __syncthreads(); }

    int t = 0;
    #pragma unroll 1
    for (int it = 0; it < 18; ++it) {
        DSTEP(t, crn1, crn0); ++t;
        DSTEP(t, crn0, crn1); ++t;
    }
#undef DSTEP

    // ---- epilogue: bias + tanh, NCHW float4 stores ----
    #pragma unroll
    for (int n = 0; n < 2; ++n) {
        int o = og * 32 + n * 16 + r0;
        float bia = b_conv[o];
        #pragma unroll
        for (int m = 0; m < 2; ++m) {
            int pxo = hw0 + m * 16 + ((lane >> 4) << 2);
            float4 v;
            v.x = fast_tanh(acc[m][n][0] + bia);
            v.y = fast_tanh(acc[m][n][1] + bia);
            v.z = fast_tanh(acc[m][n][2] + bia);
            v.w = fast_tanh(acc[m][n][3] + bia);
            *(float4*)(out + ((size_t)(b * OO + o)) * HWH + pxo) = v;
        }
    }
}

extern "C" void kernel_launch(void* const* d_in, const int* in_sizes, int n_in,
                              void* d_out, int out_size, void* d_ws, size_t ws_size,
                              hipStream_t stream) {
    const float* x      = (const float*)d_in[0];
    const float* w_off  = (const float*)d_in[1];
    const float* b_off  = (const float*)d_in[2];
    const float* w_conv = (const float*)d_in[3];
    const float* b_conv = (const float*)d_in[4];
    const float* fc1    = (const float*)d_in[5];
    const float* fc2    = (const float*)d_in[6];
    float* out = (float*)d_out;
    float* ws  = (float*)d_ws;

    float* y    = ws;                                  // 2048
    float* s    = y + 2048;                            // 2048
    float* offs = s + 2048;                            // 451584
    unsigned short* x_t = (unsigned short*)(offs + 451584);    // 6,422,528 shorts
    unsigned short* wbo = x_t + 6422528;                       // 73,728 shorts
    unsigned short* wbf = wbo + 73728;                         // 589,824 shorts
    int4*   ci = (int4*)(wbf + 589824);                        // 225,792 int4
    float4* cf = (float4*)(ci + 225792);                       // 225,792 float4

    zero_y<<<8, 256, 0, stream>>>(y);
    prep_xt<<<BB * 49 * 4, 256, 0, stream>>>(x, x_t, y);
    se_fc<<<1, 256, 0, stream>>>(y, fc1, fc2, s);
    prep_wcf<<<288, 256, 0, stream>>>(w_conv, wbf);
    prep_wo<<<36, 256, 0, stream>>>(w_off, wbo);
    offset_mfma<<<BB * 98, 256, 0, stream>>>(x_t, s, wbo, b_off, offs);
    coords_prep<<<882, 256, 0, stream>>>(offs, ci, cf);
    deform_mfma<<<BB * 98, 512, 0, stream>>>(x_t, s, ci, cf, wbf, b_conv, out);
}

// Round 10
// 137.199 us; speedup vs baseline: 2.3110x; 1.0010x over previous
//
#include <hip/hip_runtime.h>
#include <math.h>

typedef __attribute__((ext_vector_type(8))) short short8;
typedef __attribute__((ext_vector_type(8))) _Float16 h16x8;
typedef __attribute__((ext_vector_type(4))) float f32x4;

#define BB 8
#define CC 256
#define OO 256
#define HH 56
#define WW 56
#define HWH 3136
#define RED 16

__device__ inline unsigned short f2h(float f) {
    _Float16 h = (_Float16)f;
    return __builtin_bit_cast(unsigned short, h);
}
__device__ inline float h2f(unsigned short u) {
    return (float)__builtin_bit_cast(_Float16, u);
}
__device__ inline unsigned pkrtz(float lo, float hi) {
    return __builtin_bit_cast(unsigned, __builtin_amdgcn_cvt_pkrtz(lo, hi));
}
__device__ inline float fast_tanh(float x) {
    float e = __expf(2.0f * x);
    return 1.0f - 2.0f / (e + 1.0f);
}
__device__ inline void gl2lds16(const void* g, void* l) {
    __builtin_amdgcn_global_load_lds((const __attribute__((address_space(1))) unsigned int*)g,
                                     (__attribute__((address_space(3))) unsigned int*)l, 16, 0, 0);
}
// packed fp16 helpers: broadcast src1 lo/hi half via op_sel
__device__ inline unsigned pkmul_lo(unsigned a, unsigned b) {
    unsigned d;
    asm("v_pk_mul_f16 %0, %1, %2 op_sel:[0,0] op_sel_hi:[1,0]" : "=v"(d) : "v"(a), "v"(b));
    return d;
}
__device__ inline unsigned pkfma_hi(unsigned a, unsigned b, unsigned c) {
    unsigned d;
    asm("v_pk_fma_f16 %0, %1, %2, %3 op_sel:[0,1,0] op_sel_hi:[1,1,1]" : "=v"(d) : "v"(a), "v"(b), "v"(c));
    return d;
}
__device__ inline unsigned pkfma_lo(unsigned a, unsigned b, unsigned c) {
    unsigned d;
    asm("v_pk_fma_f16 %0, %1, %2, %3 op_sel:[0,0,0] op_sel_hi:[1,0,1]" : "=v"(d) : "v"(a), "v"(b), "v"(c));
    return d;
}
__device__ inline unsigned pkmul(unsigned a, unsigned b) {
    unsigned d;
    asm("v_pk_mul_f16 %0, %1, %2" : "=v"(d) : "v"(a), "v"(b));
    return d;
}
// bilinear blend of one 4-ch item (2 packed pairs), weights cw = {pk(w0,w1), pk(w2,w3)}, scale sp
__device__ inline void blend_write_h(const uint2* q, uint2 cw, uint2 sp, char* dst) {
    unsigned t0 = pkmul_lo(q[0].x, cw.x);
    t0 = pkfma_hi(q[1].x, cw.x, t0);
    t0 = pkfma_lo(q[2].x, cw.y, t0);
    t0 = pkfma_hi(q[3].x, cw.y, t0);
    t0 = pkmul(t0, sp.x);
    unsigned t1 = pkmul_lo(q[0].y, cw.x);
    t1 = pkfma_hi(q[1].y, cw.x, t1);
    t1 = pkfma_lo(q[2].y, cw.y, t1);
    t1 = pkfma_hi(q[3].y, cw.y, t1);
    t1 = pkmul(t1, sp.y);
    *(uint2*)dst = make_uint2(t0, t1);
}

// ---------------- zero y ----------------
__global__ __launch_bounds__(256) void zero_y(float* __restrict__ y) {
    y[blockIdx.x * 256 + threadIdx.x] = 0.f;
}

// ---------------- NCHW f32 -> NHWC fp16 (unscaled) + fused channel sums ----------------
__global__ __launch_bounds__(256) void prep_xt(const float* __restrict__ x, unsigned short* __restrict__ x_t,
                                               float* __restrict__ y) {
    __shared__ float t[64][65];
    int blk = blockIdx.x;
    int ct = blk & 3;
    int hwt = (blk >> 2) % 49;
    int b = blk / (4 * 49);
    int c0 = ct * 64, hw0 = hwt * 64;
    int tid = threadIdx.x;
    const float* xb = x + ((size_t)(b * CC + c0)) * HWH + hw0;
    #pragma unroll
    for (int it = 0; it < 16; ++it) {
        int idx = it * 256 + tid;
        int c = idx >> 6, px = idx & 63;
        t[c][px] = xb[(size_t)c * HWH + px];
    }
    __syncthreads();
    unsigned short* xo = x_t + ((size_t)(b * HWH + hw0)) * CC + c0;
    #pragma unroll
    for (int it = 0; it < 16; ++it) {
        int idx = it * 256 + tid;
        int px = idx >> 6, c = idx & 63;
        xo[(size_t)px * CC + c] = f2h(t[c][px]);
    }
    int c = tid >> 2, seg = tid & 3;
    float sum = 0.f;
    #pragma unroll
    for (int i = 0; i < 16; ++i) sum += t[c][seg * 16 + i];
    sum += __shfl_down(sum, 1);
    sum += __shfl_down(sum, 2);
    if (seg == 0) atomicAdd(&y[b * 256 + c0 + c], sum);
}

// ---------------- SE: fc1->relu->fc2->sigmoid (y holds sums) ----------------
__global__ __launch_bounds__(256) void se_fc(const float* __restrict__ y, const float* __restrict__ fc1,
                                             const float* __restrict__ fc2, float* __restrict__ s) {
    __shared__ float hbuf[BB * RED];
    const float inv = 1.0f / HWH;
    int t = threadIdx.x;
    if (t < BB * RED) {
        int b = t / RED, r = t % RED;
        float acc = 0.f;
        for (int c = 0; c < CC; ++c) acc += (y[b * CC + c] * inv) * fc1[r * CC + c];
        hbuf[t] = fmaxf(acc, 0.f);
    }
    __syncthreads();
    for (int i = t; i < BB * CC; i += 256) {
        int b = i / CC, c = i % CC;
        float acc = 0.f;
        #pragma unroll
        for (int r = 0; r < RED; ++r) acc += hbuf[b * RED + r] * fc2[c * RED + r];
        s[i] = 1.0f / (1.0f + expf(-acc));
    }
}

// ---------------- deform weights -> per-MFMA-fragment contiguous chunks (fp16, unscaled) ----------------
__global__ __launch_bounds__(256) void prep_wcf(const float* __restrict__ w_conv, unsigned short* __restrict__ wbf) {
    int idx = blockIdx.x * 256 + threadIdx.x;   // 73728
    int lane = idx & 63;
    int f = (idx >> 6) & 3;
    int og = (idx >> 8) & 7;
    int t = idx >> 11;
    int kk = t >> 2, cc = t & 3;
    int n = f >> 1, kh = f & 1;
    int o = og * 32 + n * 16 + (lane & 15);
    int cb2 = cc * 64 + kh * 32 + ((lane >> 4) << 3);
    short8 r;
    #pragma unroll
    for (int e = 0; e < 8; ++e) r[e] = (short)f2h(w_conv[(size_t)(o * 256 + cb2 + e) * 9 + kk]);
    *(short8*)(wbf + (size_t)idx * 8) = r;
}

// ---------------- offset weights -> 36 pre-swizzled 4KB tiles (fp16, o padded to 32) ----------------
__global__ __launch_bounds__(256) void prep_wo(const float* __restrict__ w_off, unsigned short* __restrict__ wbo) {
    int idx = blockIdx.x * 256 + threadIdx.x;    // 9216
    int g = idx & 7;
    int o = (idx >> 3) & 31;
    int t = idx >> 8;
    int kk = t >> 2, cc = t & 3;
    int dst = (((o * 128 + g * 16) ^ ((o & 7) << 4)) >> 1);
    short8 r;
    #pragma unroll
    for (int e = 0; e < 8; ++e) {
        int c = cc * 64 + g * 8 + e;
        r[e] = (o < 18) ? (short)f2h(w_off[(size_t)(o * 256 + c) * 9 + kk]) : (short)0;
    }
    *(short8*)(wbo + (size_t)t * 2048 + dst) = r;
}

// ---------------- offset conv via MFMA (fp16): 784 blocks, 32px x 32o ----------------
__global__ __launch_bounds__(256) void offset_mfma(const unsigned short* __restrict__ x_t,
                                                   const float* __restrict__ s,
                                                   const unsigned short* __restrict__ wbo,
                                                   const float* __restrict__ b_off,
                                                   float* __restrict__ offs) {
    __shared__ __align__(16) char As[4][4096];
    __shared__ __align__(16) char Bs[4][4096];
    __shared__ float red[128 * 8];
    __shared__ float s_lds[256];
    int blk = blockIdx.x;
    blk = (blk & 7) * 98 + (blk >> 3);
    int b = blk / 98;
    int hw0 = (blk % 98) * 32;
    int tid = threadIdx.x;
    int lane = tid & 63, wv = tid >> 6;
    int ks = wv >> 1, m = wv & 1;
    int r0 = lane & 15, kb = (lane >> 4) << 4;
    int px = tid >> 3, c8 = tid & 7;
    int hwp = hw0 + px;
    int hp = hwp / 56, wp_ = hwp - hp * 56;
    int awoff = (px * 128 + c8 * 16) ^ ((px & 7) << 4);
    f32x4 zero = {0.f, 0.f, 0.f, 0.f};
    f32x4 acc[2] = {zero, zero};

    s_lds[tid] = s[b * 256 + tid];
    __syncthreads();

    auto buildA = [&](int q, int r, int buf) {
        int t = q * 18 + r;
        int kk = t >> 2, cc = t & 3;
        int hh = hp + kk / 3 - 1, ww = wp_ + kk % 3 - 1;
        short8 v = {0, 0, 0, 0, 0, 0, 0, 0};
        if (hh >= 0 && hh < 56 && ww >= 0 && ww < 56)
            v = *(const short8*)(x_t + (((size_t)(b * HWH + hh * 56 + ww)) << 8) + cc * 64 + c8 * 8);
        const float* sp_ = &s_lds[cc * 64 + c8 * 8];
        unsigned p0 = pkrtz(h2f((unsigned short)v[0]) * sp_[0], h2f((unsigned short)v[1]) * sp_[1]);
        unsigned p1 = pkrtz(h2f((unsigned short)v[2]) * sp_[2], h2f((unsigned short)v[3]) * sp_[3]);
        unsigned p2 = pkrtz(h2f((unsigned short)v[4]) * sp_[4], h2f((unsigned short)v[5]) * sp_[5]);
        unsigned p3 = pkrtz(h2f((unsigned short)v[6]) * sp_[6], h2f((unsigned short)v[7]) * sp_[7]);
        *(uint4*)(As[q * 2 + buf] + awoff) = make_uint4(p0, p1, p2, p3);
    };
    auto stageB = [&](int q, int r, int buf) {
        int t = q * 18 + r;
        gl2lds16(wbo + (size_t)t * 2048 + tid * 8, Bs[q * 2 + buf] + (tid >> 6) * 1024);
    };

    stageB(0, 0, 0); stageB(1, 0, 0);
    buildA(0, 0, 0); buildA(1, 0, 0);
    __syncthreads();

    #pragma unroll 2
    for (int r = 0; r < 18; ++r) {
        int cur = r & 1;
        if (r < 17) {
            stageB(0, r + 1, cur ^ 1); stageB(1, r + 1, cur ^ 1);
            buildA(0, r + 1, cur ^ 1); buildA(1, r + 1, cur ^ 1);
        }
        h16x8 a[2];
        #pragma unroll
        for (int kh = 0; kh < 2; ++kh) {
            int row = m * 16 + r0;
            int ao = (row * 128 + kh * 64 + kb) ^ ((row & 7) << 4);
            a[kh] = __builtin_bit_cast(h16x8, *(const short8*)(As[ks * 2 + cur] + ao));
        }
        #pragma unroll
        for (int n = 0; n < 2; ++n)
            #pragma unroll
            for (int kh = 0; kh < 2; ++kh) {
                int brow = n * 16 + r0;
                int bo = (brow * 128 + kh * 64 + kb) ^ ((brow & 7) << 4);
                h16x8 bv = __builtin_bit_cast(h16x8, *(const short8*)(Bs[ks * 2 + cur] + bo));
                acc[n] = __builtin_amdgcn_mfma_f32_16x16x32_f16(a[kh], bv, acc[n], 0, 0, 0);
            }
        __syncthreads();
    }

    if (ks == 1) {
        #pragma unroll
        for (int n = 0; n < 2; ++n)
            *(f32x4*)&red[(m * 64 + lane) * 8 + n * 4] = acc[n];
    }
    __syncthreads();
    if (ks == 0) {
        #pragma unroll
        for (int n = 0; n < 2; ++n) {
            f32x4 o2 = *(const f32x4*)&red[(m * 64 + lane) * 8 + n * 4];
            acc[n] += o2;
            int o = n * 16 + r0;
            if (o < 18) {
                float bia = b_off[o];
                #pragma unroll
                for (int j = 0; j < 4; ++j)
                    offs[((size_t)(b * 18 + o)) * HWH + hw0 + m * 16 + ((lane >> 4) << 2) + j] = acc[n][j] + bia;
            }
        }
    }
}

// ---------------- precompute bilinear coords: bases (int4) + packed fp16 weights (uint2) ----------------
__global__ __launch_bounds__(256) void coords_prep(const float* __restrict__ offs,
                                                   int4* __restrict__ ci, uint2* __restrict__ cfh) {
    int idx = blockIdx.x * 256 + threadIdx.x;    // 225792
    int hw = idx % 3136;
    int t = idx / 3136;
    int kk = t % 9;
    int b = t / 9;
    int h = hw / 56, w = hw - h * 56;
    float dy = offs[((size_t)(b * 18 + kk * 2)) * HWH + hw];
    float dx = offs[((size_t)(b * 18 + kk * 2 + 1)) * HWH + hw];
    float ys = (float)(h - 1 + kk / 3) + dy;
    float xs = (float)(w - 1 + kk % 3) + dx;
    float y0f = floorf(ys), x0f = floorf(xs);
    float wy = ys - y0f, wx = xs - x0f;
    int y0 = (int)y0f, x0 = (int)x0f;
    int bi[4]; float wt[4];
    #pragma unroll
    for (int j = 0; j < 4; ++j) {
        int yj = y0 + (j >> 1), xj = x0 + (j & 1);
        bool val = yj >= 0 && yj < 56 && xj >= 0 && xj < 56;
        int yc = min(max(yj, 0), 55), xc = min(max(xj, 0), 55);
        wt[j] = val ? ((j >> 1) ? wy : 1.f - wy) * ((j & 1) ? wx : 1.f - wx) : 0.f;
        bi[j] = (b * HWH + yc * 56 + xc) << 8;
    }
    ci[idx] = make_int4(bi[0], bi[1], bi[2], bi[3]);
    cfh[idx] = make_uint2(pkrtz(wt[0], wt[1]), pkrtz(wt[2], wt[3]));
}

// ---------------- deformable conv: 784 blocks x 512 thr, 32px x 256o, fp16 packed blend ----------------
// B fragments double-buffered in registers (bv0/bv1) so the prefetch never
// overwrites the set the current MFMA consumes (r9 bug fix).
__global__ __launch_bounds__(512) void deform_mfma(const unsigned short* __restrict__ x_t,
                                                   const float* __restrict__ s,
                                                   const int4* __restrict__ ci,
                                                   const uint2* __restrict__ cfh,
                                                   const unsigned short* __restrict__ wbf,
                                                   const float* __restrict__ b_conv,
                                                   float* __restrict__ out) {
    __shared__ __align__(16) char As[8192];      // 2 x 4KB (32px x 128B)
    int blk = blockIdx.x;
    blk = (blk & 7) * 98 + (blk >> 3);           // bijective XCD swizzle
    int b = blk / 98;
    int hw0 = (blk % 98) * 32;
    int tid = threadIdx.x;
    int lane = tid & 63, og = tid >> 6;
    int px = tid >> 4, cq = tid & 15;            // A-build: 32px x 16 groups of 4ch (8B)
    int r0 = lane & 15, kb = (lane >> 4) << 4;
    int awoff = (px * 128 + cq * 8) ^ ((px & 7) << 4);
    int cidx0 = b * 9 * HWH + hw0 + px;
    const unsigned short* wbB = wbf + og * 2048 + lane * 8;

    // preload s as packed fp16 pairs for this thread's 4-ch slice per cc
    uint2 sp[4];
    #pragma unroll
    for (int cc = 0; cc < 4; ++cc) {
        float4 sv = *(const float4*)(s + b * 256 + cc * 64 + cq * 4);
        sp[cc] = make_uint2(pkrtz(sv.x, sv.y), pkrtz(sv.z, sv.w));
    }

    f32x4 zero = {0.f, 0.f, 0.f, 0.f};
    f32x4 acc[2][2];
    #pragma unroll
    for (int m = 0; m < 2; ++m)
        #pragma unroll
        for (int n = 0; n < 2; ++n) acc[m][n] = zero;

    int4 cbL = ci[cidx0];
    uint2 cwB = cfh[cidx0];
    int4 cbN = ci[cidx0 + HWH];
    uint2 cwN = cfh[cidx0 + HWH];

    uint2 crn0[4], crn1[4];
    short8 bv0[4], bv1[4];
    const unsigned short* wbK = wbB + 16384;     // ptr to B(t+1)

    // ---- prologue: blend step0 -> As[0]; load corners(step1); load B(0) -> bv0 ----
    {
        uint2 q[4];
        int c00 = cq * 4;
        q[0] = *(const uint2*)(x_t + cbL.x + c00);
        q[1] = *(const uint2*)(x_t + cbL.y + c00);
        q[2] = *(const uint2*)(x_t + cbL.z + c00);
        q[3] = *(const uint2*)(x_t + cbL.w + c00);
        int c01 = 64 + cq * 4;
        crn1[0] = *(const uint2*)(x_t + cbL.x + c01);
        crn1[1] = *(const uint2*)(x_t + cbL.y + c01);
        crn1[2] = *(const uint2*)(x_t + cbL.z + c01);
        crn1[3] = *(const uint2*)(x_t + cbL.w + c01);
        #pragma unroll
        for (int f = 0; f < 4; ++f) bv0[f] = *(const short8*)(wbB + f * 512);
        blend_write_h(q, cwB, sp[0], As + awoff);
    }
    __syncthreads();

#define PHASE(CCV, CBLEND, CLOAD, BVC, BVL) { \
    constexpr int CCc = (CCV); \
    h16x8 a_[2][2]; \
    { constexpr int tb_ = (CCc & 1) * 4096; \
      _Pragma("unroll") for (int m_ = 0; m_ < 2; ++m_) \
      _Pragma("unroll") for (int kh_ = 0; kh_ < 2; ++kh_) { \
        int row_ = m_ * 16 + r0; \
        int ao_ = (row_ * 128 + kh_ * 64 + kb) ^ ((row_ & 7) << 4); \
        a_[m_][kh_] = __builtin_bit_cast(h16x8, *(const short8*)(As + tb_ + ao_)); } } \
    if (kk < 8 || CCc < 3) { \
        _Pragma("unroll") for (int f_ = 0; f_ < 4; ++f_) BVL[f_] = *(const short8*)(wbK + f_ * 512); } \
    wbK += 16384; \
    _Pragma("unroll") for (int n_ = 0; n_ < 2; ++n_) \
      _Pragma("unroll") for (int kh_ = 0; kh_ < 2; ++kh_) \
        _Pragma("unroll") for (int m_ = 0; m_ < 2; ++m_) \
          acc[m_][n_] = __builtin_amdgcn_mfma_f32_16x16x32_f16(a_[m_][kh_], __builtin_bit_cast(h16x8, BVC[n_ * 2 + kh_]), acc[m_][n_], 0, 0, 0); \
    if (kk < 8 || CCc < 3) { \
        if (CCc == 3) cwB = cwN; \
        blend_write_h(CBLEND, cwB, sp[(CCc + 1) & 3], As + ((CCc + 1) & 1) * 4096 + awoff); } \
    if (kk < 8 || CCc < 2) { \
        if (CCc == 2) cbL = cbN; \
        constexpr int c0_ = (((CCc) + 2) & 3) * 64; \
        CLOAD[0] = *(const uint2*)(x_t + cbL.x + c0_ + cq * 4); \
        CLOAD[1] = *(const uint2*)(x_t + cbL.y + c0_ + cq * 4); \
        CLOAD[2] = *(const uint2*)(x_t + cbL.z + c0_ + cq * 4); \
        CLOAD[3] = *(const uint2*)(x_t + cbL.w + c0_ + cq * 4); } \
    if (CCc == 1 && kk < 8) { \
        int cidx = cidx0 + (kk + 1) * HWH; \
        cbN = ci[cidx]; cwN = cfh[cidx]; } \
    __syncthreads(); }

    #pragma unroll 1
    for (int kk = 0; kk < 9; ++kk) {
        PHASE(0, crn1, crn0, bv0, bv1);
        PHASE(1, crn0, crn1, bv1, bv0);
        PHASE(2, crn1, crn0, bv0, bv1);
        PHASE(3, crn0, crn1, bv1, bv0);
    }
#undef PHASE

    // ---- epilogue: bias + tanh, NCHW float4 stores ----
    #pragma unroll
    for (int n = 0; n < 2; ++n) {
        int o = og * 32 + n * 16 + r0;
        float bia = b_conv[o];
        #pragma unroll
        for (int m = 0; m < 2; ++m) {
            int pxo = hw0 + m * 16 + ((lane >> 4) << 2);
            float4 v;
            v.x = fast_tanh(acc[m][n][0] + bia);
            v.y = fast_tanh(acc[m][n][1] + bia);
            v.z = fast_tanh(acc[m][n][2] + bia);
            v.w = fast_tanh(acc[m][n][3] + bia);
            *(float4*)(out + ((size_t)(b * OO + o)) * HWH + pxo) = v;
        }
    }
}

extern "C" void kernel_launch(void* const* d_in, const int* in_sizes, int n_in,
                              void* d_out, int out_size, void* d_ws, size_t ws_size,
                              hipStream_t stream) {
    const float* x      = (const float*)d_in[0];
    const float* w_off  = (const float*)d_in[1];
    const float* b_off  = (const float*)d_in[2];
    const float* w_conv = (const float*)d_in[3];
    const float* b_conv = (const float*)d_in[4];
    const float* fc1    = (const float*)d_in[5];
    const float* fc2    = (const float*)d_in[6];
    float* out = (float*)d_out;
    float* ws  = (float*)d_ws;

    float* y    = ws;                                  // 2048
    float* s    = y + 2048;                            // 2048
    float* offs = s + 2048;                            // 451584
    unsigned short* x_t = (unsigned short*)(offs + 451584);    // 6,422,528 shorts (fp16)
    unsigned short* wbo = x_t + 6422528;                       // 73,728 shorts
    unsigned short* wbf = wbo + 73728;                         // 589,824 shorts
    int4*  ci  = (int4*)(wbf + 589824);                        // 225,792 int4
    uint2* cfh = (uint2*)(ci + 225792);                        // 225,792 uint2

    zero_y<<<8, 256, 0, stream>>>(y);
    prep_xt<<<BB * 49 * 4, 256, 0, stream>>>(x, x_t, y);
    se_fc<<<1, 256, 0, stream>>>(y, fc1, fc2, s);
    prep_wcf<<<288, 256, 0, stream>>>(w_conv, wbf);
    prep_wo<<<36, 256, 0, stream>>>(w_off, wbo);
    offset_mfma<<<BB * 98, 256, 0, stream>>>(x_t, s, wbo, b_off, offs);
    coords_prep<<<882, 256, 0, stream>>>(offs, ci, cfh);
    deform_mfma<<<BB * 98, 512, 0, stream>>>(x_t, s, ci, cfh, wbf, b_conv, out);
}

// Round 11
// 136.858 us; speedup vs baseline: 2.3168x; 1.0025x over previous
//
#include <hip/hip_runtime.h>
#include <math.h>

typedef __attribute__((ext_vector_type(8))) short short8;
typedef __attribute__((ext_vector_type(8))) _Float16 h16x8;
typedef __attribute__((ext_vector_type(4))) float f32x4;

#define BB 8
#define CC 256
#define OO 256
#define HH 56
#define WW 56
#define HWH 3136
#define RED 16

__device__ inline unsigned short f2h(float f) {
    _Float16 h = (_Float16)f;
    return __builtin_bit_cast(unsigned short, h);
}
__device__ inline float h2f(unsigned short u) {
    return (float)__builtin_bit_cast(_Float16, u);
}
__device__ inline unsigned pkrtz(float lo, float hi) {
    return __builtin_bit_cast(unsigned, __builtin_amdgcn_cvt_pkrtz(lo, hi));
}
__device__ inline float fast_tanh(float x) {
    float e = __expf(2.0f * x);
    return 1.0f - 2.0f / (e + 1.0f);
}
__device__ inline void gl2lds16(const void* g, void* l) {
    __builtin_amdgcn_global_load_lds((const __attribute__((address_space(1))) unsigned int*)g,
                                     (__attribute__((address_space(3))) unsigned int*)l, 16, 0, 0);
}
// barrier that drains ONLY LDS ops; global prefetch loads stay in flight (T4)
__device__ inline void phase_barrier() {
    __builtin_amdgcn_sched_barrier(0);
    asm volatile("s_waitcnt lgkmcnt(0)" ::: "memory");
    __builtin_amdgcn_s_barrier();
    __builtin_amdgcn_sched_barrier(0);
}
// packed fp16 helpers: broadcast src1 lo/hi half via op_sel
__device__ inline unsigned pkmul_lo(unsigned a, unsigned b) {
    unsigned d;
    asm("v_pk_mul_f16 %0, %1, %2 op_sel:[0,0] op_sel_hi:[1,0]" : "=v"(d) : "v"(a), "v"(b));
    return d;
}
__device__ inline unsigned pkfma_hi(unsigned a, unsigned b, unsigned c) {
    unsigned d;
    asm("v_pk_fma_f16 %0, %1, %2, %3 op_sel:[0,1,0] op_sel_hi:[1,1,1]" : "=v"(d) : "v"(a), "v"(b), "v"(c));
    return d;
}
__device__ inline unsigned pkfma_lo(unsigned a, unsigned b, unsigned c) {
    unsigned d;
    asm("v_pk_fma_f16 %0, %1, %2, %3 op_sel:[0,0,0] op_sel_hi:[1,0,1]" : "=v"(d) : "v"(a), "v"(b), "v"(c));
    return d;
}
__device__ inline unsigned pkmul(unsigned a, unsigned b) {
    unsigned d;
    asm("v_pk_mul_f16 %0, %1, %2" : "=v"(d) : "v"(a), "v"(b));
    return d;
}
// bilinear blend of one 4-ch item (2 packed pairs), weights cw = {pk(w0,w1), pk(w2,w3)}, scale sp
__device__ inline void blend_write_h(const uint2* q, uint2 cw, uint2 sp, char* dst) {
    unsigned t0 = pkmul_lo(q[0].x, cw.x);
    t0 = pkfma_hi(q[1].x, cw.x, t0);
    t0 = pkfma_lo(q[2].x, cw.y, t0);
    t0 = pkfma_hi(q[3].x, cw.y, t0);
    t0 = pkmul(t0, sp.x);
    unsigned t1 = pkmul_lo(q[0].y, cw.x);
    t1 = pkfma_hi(q[1].y, cw.x, t1);
    t1 = pkfma_lo(q[2].y, cw.y, t1);
    t1 = pkfma_hi(q[3].y, cw.y, t1);
    t1 = pkmul(t1, sp.y);
    *(uint2*)dst = make_uint2(t0, t1);
}

// ---------------- zero y ----------------
__global__ __launch_bounds__(256) void zero_y(float* __restrict__ y) {
    y[blockIdx.x * 256 + threadIdx.x] = 0.f;
}

// ---------------- NCHW f32 -> NHWC fp16 (unscaled) + fused channel sums ----------------
__global__ __launch_bounds__(256) void prep_xt(const float* __restrict__ x, unsigned short* __restrict__ x_t,
                                               float* __restrict__ y) {
    __shared__ float t[64][65];
    int blk = blockIdx.x;
    int ct = blk & 3;
    int hwt = (blk >> 2) % 49;
    int b = blk / (4 * 49);
    int c0 = ct * 64, hw0 = hwt * 64;
    int tid = threadIdx.x;
    const float* xb = x + ((size_t)(b * CC + c0)) * HWH + hw0;
    #pragma unroll
    for (int it = 0; it < 16; ++it) {
        int idx = it * 256 + tid;
        int c = idx >> 6, px = idx & 63;
        t[c][px] = xb[(size_t)c * HWH + px];
    }
    __syncthreads();
    unsigned short* xo = x_t + ((size_t)(b * HWH + hw0)) * CC + c0;
    #pragma unroll
    for (int it = 0; it < 16; ++it) {
        int idx = it * 256 + tid;
        int px = idx >> 6, c = idx & 63;
        xo[(size_t)px * CC + c] = f2h(t[c][px]);
    }
    int c = tid >> 2, seg = tid & 3;
    float sum = 0.f;
    #pragma unroll
    for (int i = 0; i < 16; ++i) sum += t[c][seg * 16 + i];
    sum += __shfl_down(sum, 1);
    sum += __shfl_down(sum, 2);
    if (seg == 0) atomicAdd(&y[b * 256 + c0 + c], sum);
}

// ---------------- SE: fc1->relu->fc2->sigmoid (y holds sums) ----------------
__global__ __launch_bounds__(256) void se_fc(const float* __restrict__ y, const float* __restrict__ fc1,
                                             const float* __restrict__ fc2, float* __restrict__ s) {
    __shared__ float hbuf[BB * RED];
    const float inv = 1.0f / HWH;
    int t = threadIdx.x;
    if (t < BB * RED) {
        int b = t / RED, r = t % RED;
        float acc = 0.f;
        for (int c = 0; c < CC; ++c) acc += (y[b * CC + c] * inv) * fc1[r * CC + c];
        hbuf[t] = fmaxf(acc, 0.f);
    }
    __syncthreads();
    for (int i = t; i < BB * CC; i += 256) {
        int b = i / CC, c = i % CC;
        float acc = 0.f;
        #pragma unroll
        for (int r = 0; r < RED; ++r) acc += hbuf[b * RED + r] * fc2[c * RED + r];
        s[i] = 1.0f / (1.0f + expf(-acc));
    }
}

// ---------------- deform weights -> per-MFMA-fragment contiguous chunks (fp16, unscaled) ----------------
__global__ __launch_bounds__(256) void prep_wcf(const float* __restrict__ w_conv, unsigned short* __restrict__ wbf) {
    int idx = blockIdx.x * 256 + threadIdx.x;   // 73728
    int lane = idx & 63;
    int f = (idx >> 6) & 3;
    int og = (idx >> 8) & 7;
    int t = idx >> 11;
    int kk = t >> 2, cc = t & 3;
    int n = f >> 1, kh = f & 1;
    int o = og * 32 + n * 16 + (lane & 15);
    int cb2 = cc * 64 + kh * 32 + ((lane >> 4) << 3);
    short8 r;
    #pragma unroll
    for (int e = 0; e < 8; ++e) r[e] = (short)f2h(w_conv[(size_t)(o * 256 + cb2 + e) * 9 + kk]);
    *(short8*)(wbf + (size_t)idx * 8) = r;
}

// ---------------- offset weights -> 36 pre-swizzled 4KB tiles (fp16, o padded to 32) ----------------
__global__ __launch_bounds__(256) void prep_wo(const float* __restrict__ w_off, unsigned short* __restrict__ wbo) {
    int idx = blockIdx.x * 256 + threadIdx.x;    // 9216
    int g = idx & 7;
    int o = (idx >> 3) & 31;
    int t = idx >> 8;
    int kk = t >> 2, cc = t & 3;
    int dst = (((o * 128 + g * 16) ^ ((o & 7) << 4)) >> 1);
    short8 r;
    #pragma unroll
    for (int e = 0; e < 8; ++e) {
        int c = cc * 64 + g * 8 + e;
        r[e] = (o < 18) ? (short)f2h(w_off[(size_t)(o * 256 + c) * 9 + kk]) : (short)0;
    }
    *(short8*)(wbo + (size_t)t * 2048 + dst) = r;
}

// ---------------- offset conv via MFMA (fp16): 784 blocks, 32px x 32o ----------------
__global__ __launch_bounds__(256) void offset_mfma(const unsigned short* __restrict__ x_t,
                                                   const float* __restrict__ s,
                                                   const unsigned short* __restrict__ wbo,
                                                   const float* __restrict__ b_off,
                                                   float* __restrict__ offs) {
    __shared__ __align__(16) char As[4][4096];
    __shared__ __align__(16) char Bs[4][4096];
    __shared__ float red[128 * 8];
    __shared__ float s_lds[256];
    int blk = blockIdx.x;
    blk = (blk & 7) * 98 + (blk >> 3);
    int b = blk / 98;
    int hw0 = (blk % 98) * 32;
    int tid = threadIdx.x;
    int lane = tid & 63, wv = tid >> 6;
    int ks = wv >> 1, m = wv & 1;
    int r0 = lane & 15, kb = (lane >> 4) << 4;
    int px = tid >> 3, c8 = tid & 7;
    int hwp = hw0 + px;
    int hp = hwp / 56, wp_ = hwp - hp * 56;
    int awoff = (px * 128 + c8 * 16) ^ ((px & 7) << 4);
    f32x4 zero = {0.f, 0.f, 0.f, 0.f};
    f32x4 acc[2] = {zero, zero};

    s_lds[tid] = s[b * 256 + tid];
    __syncthreads();

    auto buildA = [&](int q, int r, int buf) {
        int t = q * 18 + r;
        int kk = t >> 2, cc = t & 3;
        int hh = hp + kk / 3 - 1, ww = wp_ + kk % 3 - 1;
        short8 v = {0, 0, 0, 0, 0, 0, 0, 0};
        if (hh >= 0 && hh < 56 && ww >= 0 && ww < 56)
            v = *(const short8*)(x_t + (((size_t)(b * HWH + hh * 56 + ww)) << 8) + cc * 64 + c8 * 8);
        const float* sp_ = &s_lds[cc * 64 + c8 * 8];
        unsigned p0 = pkrtz(h2f((unsigned short)v[0]) * sp_[0], h2f((unsigned short)v[1]) * sp_[1]);
        unsigned p1 = pkrtz(h2f((unsigned short)v[2]) * sp_[2], h2f((unsigned short)v[3]) * sp_[3]);
        unsigned p2 = pkrtz(h2f((unsigned short)v[4]) * sp_[4], h2f((unsigned short)v[5]) * sp_[5]);
        unsigned p3 = pkrtz(h2f((unsigned short)v[6]) * sp_[6], h2f((unsigned short)v[7]) * sp_[7]);
        *(uint4*)(As[q * 2 + buf] + awoff) = make_uint4(p0, p1, p2, p3);
    };
    auto stageB = [&](int q, int r, int buf) {
        int t = q * 18 + r;
        gl2lds16(wbo + (size_t)t * 2048 + tid * 8, Bs[q * 2 + buf] + (tid >> 6) * 1024);
    };

    stageB(0, 0, 0); stageB(1, 0, 0);
    buildA(0, 0, 0); buildA(1, 0, 0);
    __syncthreads();

    #pragma unroll 2
    for (int r = 0; r < 18; ++r) {
        int cur = r & 1;
        if (r < 17) {
            stageB(0, r + 1, cur ^ 1); stageB(1, r + 1, cur ^ 1);
            buildA(0, r + 1, cur ^ 1); buildA(1, r + 1, cur ^ 1);
        }
        h16x8 a[2];
        #pragma unroll
        for (int kh = 0; kh < 2; ++kh) {
            int row = m * 16 + r0;
            int ao = (row * 128 + kh * 64 + kb) ^ ((row & 7) << 4);
            a[kh] = __builtin_bit_cast(h16x8, *(const short8*)(As[ks * 2 + cur] + ao));
        }
        #pragma unroll
        for (int n = 0; n < 2; ++n)
            #pragma unroll
            for (int kh = 0; kh < 2; ++kh) {
                int brow = n * 16 + r0;
                int bo = (brow * 128 + kh * 64 + kb) ^ ((brow & 7) << 4);
                h16x8 bv = __builtin_bit_cast(h16x8, *(const short8*)(Bs[ks * 2 + cur] + bo));
                acc[n] = __builtin_amdgcn_mfma_f32_16x16x32_f16(a[kh], bv, acc[n], 0, 0, 0);
            }
        __syncthreads();
    }

    if (ks == 1) {
        #pragma unroll
        for (int n = 0; n < 2; ++n)
            *(f32x4*)&red[(m * 64 + lane) * 8 + n * 4] = acc[n];
    }
    __syncthreads();
    if (ks == 0) {
        #pragma unroll
        for (int n = 0; n < 2; ++n) {
            f32x4 o2 = *(const f32x4*)&red[(m * 64 + lane) * 8 + n * 4];
            acc[n] += o2;
            int o = n * 16 + r0;
            if (o < 18) {
                float bia = b_off[o];
                #pragma unroll
                for (int j = 0; j < 4; ++j)
                    offs[((size_t)(b * 18 + o)) * HWH + hw0 + m * 16 + ((lane >> 4) << 2) + j] = acc[n][j] + bia;
            }
        }
    }
}

// ---------------- precompute bilinear coords: bases (int4) + packed fp16 weights (uint2) ----------------
__global__ __launch_bounds__(256) void coords_prep(const float* __restrict__ offs,
                                                   int4* __restrict__ ci, uint2* __restrict__ cfh) {
    int idx = blockIdx.x * 256 + threadIdx.x;    // 225792
    int hw = idx % 3136;
    int t = idx / 3136;
    int kk = t % 9;
    int b = t / 9;
    int h = hw / 56, w = hw - h * 56;
    float dy = offs[((size_t)(b * 18 + kk * 2)) * HWH + hw];
    float dx = offs[((size_t)(b * 18 + kk * 2 + 1)) * HWH + hw];
    float ys = (float)(h - 1 + kk / 3) + dy;
    float xs = (float)(w - 1 + kk % 3) + dx;
    float y0f = floorf(ys), x0f = floorf(xs);
    float wy = ys - y0f, wx = xs - x0f;
    int y0 = (int)y0f, x0 = (int)x0f;
    int bi[4]; float wt[4];
    #pragma unroll
    for (int j = 0; j < 4; ++j) {
        int yj = y0 + (j >> 1), xj = x0 + (j & 1);
        bool val = yj >= 0 && yj < 56 && xj >= 0 && xj < 56;
        int yc = min(max(yj, 0), 55), xc = min(max(xj, 0), 55);
        wt[j] = val ? ((j >> 1) ? wy : 1.f - wy) * ((j & 1) ? wx : 1.f - wx) : 0.f;
        bi[j] = (b * HWH + yc * 56 + xc) << 8;
    }
    ci[idx] = make_int4(bi[0], bi[1], bi[2], bi[3]);
    cfh[idx] = make_uint2(pkrtz(wt[0], wt[1]), pkrtz(wt[2], wt[3]));
}

// ---------------- deformable conv: 784 blocks x 512 thr, 32px x 256o, fp16 packed blend ----------------
// r11: phase barrier drains ONLY lgkmcnt; global prefetch (B, corners, coords)
// stays in flight across the barrier (the vmcnt(0)-at-__syncthreads drain was
// the ~4200cyc/phase stall identified in r10's post-mortem).
__global__ __launch_bounds__(512) void deform_mfma(const unsigned short* __restrict__ x_t,
                                                   const float* __restrict__ s,
                                                   const int4* __restrict__ ci,
                                                   const uint2* __restrict__ cfh,
                                                   const unsigned short* __restrict__ wbf,
                                                   const float* __restrict__ b_conv,
                                                   float* __restrict__ out) {
    __shared__ __align__(16) char As[8192];      // 2 x 4KB (32px x 128B)
    int blk = blockIdx.x;
    blk = (blk & 7) * 98 + (blk >> 3);           // bijective XCD swizzle
    int b = blk / 98;
    int hw0 = (blk % 98) * 32;
    int tid = threadIdx.x;
    int lane = tid & 63, og = tid >> 6;
    int px = tid >> 4, cq = tid & 15;            // A-build: 32px x 16 groups of 4ch (8B)
    int r0 = lane & 15, kb = (lane >> 4) << 4;
    int awoff = (px * 128 + cq * 8) ^ ((px & 7) << 4);
    int cidx0 = b * 9 * HWH + hw0 + px;
    const unsigned short* wbB = wbf + og * 2048 + lane * 8;

    // preload s as packed fp16 pairs for this thread's 4-ch slice per cc
    uint2 sp[4];
    #pragma unroll
    for (int cc = 0; cc < 4; ++cc) {
        float4 sv = *(const float4*)(s + b * 256 + cc * 64 + cq * 4);
        sp[cc] = make_uint2(pkrtz(sv.x, sv.y), pkrtz(sv.z, sv.w));
    }

    f32x4 zero = {0.f, 0.f, 0.f, 0.f};
    f32x4 acc[2][2];
    #pragma unroll
    for (int m = 0; m < 2; ++m)
        #pragma unroll
        for (int n = 0; n < 2; ++n) acc[m][n] = zero;

    int4 cbL = ci[cidx0];
    uint2 cwB = cfh[cidx0];
    int4 cbN = ci[cidx0 + HWH];
    uint2 cwN = cfh[cidx0 + HWH];

    uint2 crn0[4], crn1[4];
    short8 bv0[4], bv1[4];
    const unsigned short* wbK = wbB + 16384;     // ptr to B(t+1)

    // ---- prologue: blend step0 -> As[0]; load corners(step1); load B(0) -> bv0 ----
    {
        uint2 q[4];
        int c00 = cq * 4;
        q[0] = *(const uint2*)(x_t + cbL.x + c00);
        q[1] = *(const uint2*)(x_t + cbL.y + c00);
        q[2] = *(const uint2*)(x_t + cbL.z + c00);
        q[3] = *(const uint2*)(x_t + cbL.w + c00);
        int c01 = 64 + cq * 4;
        crn1[0] = *(const uint2*)(x_t + cbL.x + c01);
        crn1[1] = *(const uint2*)(x_t + cbL.y + c01);
        crn1[2] = *(const uint2*)(x_t + cbL.z + c01);
        crn1[3] = *(const uint2*)(x_t + cbL.w + c01);
        #pragma unroll
        for (int f = 0; f < 4; ++f) bv0[f] = *(const short8*)(wbB + f * 512);
        blend_write_h(q, cwB, sp[0], As + awoff);
    }
    phase_barrier();

#define PHASE(CCV, CBLEND, CLOAD, BVC, BVL) { \
    constexpr int CCc = (CCV); \
    h16x8 a_[2][2]; \
    { constexpr int tb_ = (CCc & 1) * 4096; \
      _Pragma("unroll") for (int m_ = 0; m_ < 2; ++m_) \
      _Pragma("unroll") for (int kh_ = 0; kh_ < 2; ++kh_) { \
        int row_ = m_ * 16 + r0; \
        int ao_ = (row_ * 128 + kh_ * 64 + kb) ^ ((row_ & 7) << 4); \
        a_[m_][kh_] = __builtin_bit_cast(h16x8, *(const short8*)(As + tb_ + ao_)); } } \
    if (kk < 8 || CCc < 3) { \
        _Pragma("unroll") for (int f_ = 0; f_ < 4; ++f_) BVL[f_] = *(const short8*)(wbK + f_ * 512); } \
    wbK += 16384; \
    _Pragma("unroll") for (int n_ = 0; n_ < 2; ++n_) \
      _Pragma("unroll") for (int kh_ = 0; kh_ < 2; ++kh_) \
        _Pragma("unroll") for (int m_ = 0; m_ < 2; ++m_) \
          acc[m_][n_] = __builtin_amdgcn_mfma_f32_16x16x32_f16(a_[m_][kh_], __builtin_bit_cast(h16x8, BVC[n_ * 2 + kh_]), acc[m_][n_], 0, 0, 0); \
    if (kk < 8 || CCc < 3) { \
        if (CCc == 3) cwB = cwN; \
        blend_write_h(CBLEND, cwB, sp[(CCc + 1) & 3], As + ((CCc + 1) & 1) * 4096 + awoff); } \
    if (kk < 8 || CCc < 2) { \
        if (CCc == 2) cbL = cbN; \
        constexpr int c0_ = (((CCc) + 2) & 3) * 64; \
        CLOAD[0] = *(const uint2*)(x_t + cbL.x + c0_ + cq * 4); \
        CLOAD[1] = *(const uint2*)(x_t + cbL.y + c0_ + cq * 4); \
        CLOAD[2] = *(const uint2*)(x_t + cbL.z + c0_ + cq * 4); \
        CLOAD[3] = *(const uint2*)(x_t + cbL.w + c0_ + cq * 4); } \
    if (CCc == 1 && kk < 8) { \
        int cidx = cidx0 + (kk + 1) * HWH; \
        cbN = ci[cidx]; cwN = cfh[cidx]; } \
    phase_barrier(); }

    #pragma unroll 1
    for (int kk = 0; kk < 9; ++kk) {
        PHASE(0, crn1, crn0, bv0, bv1);
        PHASE(1, crn0, crn1, bv1, bv0);
        PHASE(2, crn1, crn0, bv0, bv1);
        PHASE(3, crn0, crn1, bv1, bv0);
    }
#undef PHASE

    // ---- epilogue: bias + tanh, NCHW float4 stores ----
    #pragma unroll
    for (int n = 0; n < 2; ++n) {
        int o = og * 32 + n * 16 + r0;
        float bia = b_conv[o];
        #pragma unroll
        for (int m = 0; m < 2; ++m) {
            int pxo = hw0 + m * 16 + ((lane >> 4) << 2);
            float4 v;
            v.x = fast_tanh(acc[m][n][0] + bia);
            v.y = fast_tanh(acc[m][n][1] + bia);
            v.z = fast_tanh(acc[m][n][2] + bia);
            v.w = fast_tanh(acc[m][n][3] + bia);
            *(float4*)(out + ((size_t)(b * OO + o)) * HWH + pxo) = v;
        }
    }
}

extern "C" void kernel_launch(void* const* d_in, const int* in_sizes, int n_in,
                              void* d_out, int out_size, void* d_ws, size_t ws_size,
                              hipStream_t stream) {
    const float* x      = (const float*)d_in[0];
    const float* w_off  = (const float*)d_in[1];
    const float* b_off  = (const float*)d_in[2];
    const float* w_conv = (const float*)d_in[3];
    const float* b_conv = (const float*)d_in[4];
    const float* fc1    = (const float*)d_in[5];
    const float* fc2    = (const float*)d_in[6];
    float* out = (float*)d_out;
    float* ws  = (float*)d_ws;

    float* y    = ws;                                  // 2048
    float* s    = y + 2048;                            // 2048
    float* offs = s + 2048;                            // 451584
    unsigned short* x_t = (unsigned short*)(offs + 451584);    // 6,422,528 shorts (fp16)
    unsigned short* wbo = x_t + 6422528;                       // 73,728 shorts
    unsigned short* wbf = wbo + 73728;                         // 589,824 shorts
    int4*  ci  = (int4*)(wbf + 589824);                        // 225,792 int4
    uint2* cfh = (uint2*)(ci + 225792);                        // 225,792 uint2

    zero_y<<<8, 256, 0, stream>>>(y);
    prep_xt<<<BB * 49 * 4, 256, 0, stream>>>(x, x_t, y);
    se_fc<<<1, 256, 0, stream>>>(y, fc1, fc2, s);
    prep_wcf<<<288, 256, 0, stream>>>(w_conv, wbf);
    prep_wo<<<36, 256, 0, stream>>>(w_off, wbo);
    offset_mfma<<<BB * 98, 256, 0, stream>>>(x_t, s, wbo, b_off, offs);
    coords_prep<<<882, 256, 0, stream>>>(offs, ci, cfh);
    deform_mfma<<<BB * 98, 512, 0, stream>>>(x_t, s, ci, cfh, wbf, b_conv, out);
}